// Round 1
// baseline (609.171 us; speedup 1.0000x reference)
//
#include <hip/hip_runtime.h>
#include <hip/hip_bf16.h>
#include <math.h>

#define N_ROWS 65536
#define PSI    1024
#define DDIM   256

// ---------- helpers: total-order float <-> uint for atomicMin ----------
__device__ __forceinline__ unsigned fkey(float f) {
    unsigned u = __float_as_uint(f);
    return (u & 0x80000000u) ? ~u : (u | 0x80000000u);
}
__device__ __forceinline__ float kinv(unsigned k) {
    unsigned u = (k & 0x80000000u) ? (k ^ 0x80000000u) : ~k;
    return __uint_as_float(u);
}

// ---------- K0: init stats ----------
__global__ void k_init(unsigned* __restrict__ minkey, float* __restrict__ sumexp) {
    int i = blockIdx.x * blockDim.x + threadIdx.x;
    if (i < PSI) { minkey[i] = 0xFFFFFFFFu; sumexp[i] = 0.0f; }
}

// ---------- row squared-norms: one wave per row ----------
__global__ void k_rownorm(const float* __restrict__ A, float* __restrict__ out, int rows) {
    int wave = (blockIdx.x * blockDim.x + threadIdx.x) >> 6;
    int lane = threadIdx.x & 63;
    if (wave >= rows) return;
    const float4 v = *(const float4*)&A[(size_t)wave * DDIM + lane * 4];
    float s = v.x * v.x + v.y * v.y + v.z * v.z + v.w * v.w;
    #pragma unroll
    for (int o = 32; o > 0; o >>= 1) s += __shfl_down(s, o);
    if (lane == 0) out[wave] = s;
}

// ---------- K1: GEMM -> m = sqrt(max(x2+s2-2*dot,0))*w ; write out + col-min ----------
#define BM 128
#define BN 64
#define BK 16

__global__ __launch_bounds__(256) void k_gemm_min(
    const float* __restrict__ X, const float* __restrict__ S,
    const float* __restrict__ w, const float* __restrict__ x2,
    const float* __restrict__ s2, float* __restrict__ out,
    unsigned* __restrict__ minkey)
{
    __shared__ float As[BK][BM];     // 8 KB, K-major
    __shared__ float Bs[BK][BN];     // 4 KB
    __shared__ unsigned cmin[BN];

    const int tid  = threadIdx.x;
    const int col0 = blockIdx.x * BN;
    const int row0 = blockIdx.y * BM;

    if (tid < BN) cmin[tid] = 0xFFFFFFFFu;

    const int tx = tid & 15;   // column quad: cols tx*4..tx*4+3
    const int ty = tid >> 4;   // row quad: rows ty*4..+3 and 64+ty*4..+3

    float acc[8][4];
    #pragma unroll
    for (int i = 0; i < 8; ++i)
        #pragma unroll
        for (int j = 0; j < 4; ++j) acc[i][j] = 0.0f;

    // staging: A tile 128x16 = 512 float4s, thread loads f4-ids tid and tid+256
    const int ar0 = tid >> 2;             // rows 0..63
    const int ar1 = (tid >> 2) + 64;      // rows 64..127
    const int akq = (tid & 3) * 4;        // k offset 0/4/8/12
    const int br  = tid >> 2;             // B rows 0..63
    // (B tile 64x16 = 256 float4s, one per thread)

    for (int k0 = 0; k0 < DDIM; k0 += BK) {
        const float4 a0 = *(const float4*)&X[(size_t)(row0 + ar0) * DDIM + k0 + akq];
        const float4 a1 = *(const float4*)&X[(size_t)(row0 + ar1) * DDIM + k0 + akq];
        const float4 b0 = *(const float4*)&S[(size_t)(col0 + br)  * DDIM + k0 + akq];
        __syncthreads();
        As[akq + 0][ar0] = a0.x; As[akq + 1][ar0] = a0.y;
        As[akq + 2][ar0] = a0.z; As[akq + 3][ar0] = a0.w;
        As[akq + 0][ar1] = a1.x; As[akq + 1][ar1] = a1.y;
        As[akq + 2][ar1] = a1.z; As[akq + 3][ar1] = a1.w;
        Bs[akq + 0][br]  = b0.x; Bs[akq + 1][br]  = b0.y;
        Bs[akq + 2][br]  = b0.z; Bs[akq + 3][br]  = b0.w;
        __syncthreads();
        #pragma unroll
        for (int kk = 0; kk < BK; ++kk) {
            const float4 av0 = *(const float4*)&As[kk][ty * 4];
            const float4 av1 = *(const float4*)&As[kk][64 + ty * 4];
            const float4 bv  = *(const float4*)&Bs[kk][tx * 4];
            float a[8] = {av0.x, av0.y, av0.z, av0.w, av1.x, av1.y, av1.z, av1.w};
            float b[4] = {bv.x, bv.y, bv.z, bv.w};
            #pragma unroll
            for (int i = 0; i < 8; ++i)
                #pragma unroll
                for (int j = 0; j < 4; ++j)
                    acc[i][j] = fmaf(a[i], b[j], acc[i][j]);
        }
    }

    // epilogue
    float x2r[8];
    #pragma unroll
    for (int i = 0; i < 4; ++i) {
        x2r[i]     = x2[row0 + ty * 4 + i];
        x2r[4 + i] = x2[row0 + 64 + ty * 4 + i];
    }
    const float4 s2v = *(const float4*)&s2[col0 + tx * 4];
    const float4 wv  = *(const float4*)&w[col0 + tx * 4];

    float cm[4] = {INFINITY, INFINITY, INFINITY, INFINITY};
    #pragma unroll
    for (int i = 0; i < 8; ++i) {
        const int r = (i < 4) ? (ty * 4 + i) : (64 + ty * 4 + (i - 4));
        float4 mv;
        mv.x = sqrtf(fmaxf(x2r[i] + s2v.x - 2.0f * acc[i][0], 0.0f)) * wv.x;
        mv.y = sqrtf(fmaxf(x2r[i] + s2v.y - 2.0f * acc[i][1], 0.0f)) * wv.y;
        mv.z = sqrtf(fmaxf(x2r[i] + s2v.z - 2.0f * acc[i][2], 0.0f)) * wv.z;
        mv.w = sqrtf(fmaxf(x2r[i] + s2v.w - 2.0f * acc[i][3], 0.0f)) * wv.w;
        *(float4*)&out[(size_t)(row0 + r) * PSI + col0 + tx * 4] = mv;
        cm[0] = fminf(cm[0], mv.x); cm[1] = fminf(cm[1], mv.y);
        cm[2] = fminf(cm[2], mv.z); cm[3] = fminf(cm[3], mv.w);
    }
    #pragma unroll
    for (int j = 0; j < 4; ++j) atomicMin(&cmin[tx * 4 + j], fkey(cm[j]));
    __syncthreads();
    if (tid < BN) atomicMin(&minkey[col0 + tid], cmin[tid]);
}

// ---------- K2: column sums of exp(min - m) ----------
#define SUM_ROWS 256
__global__ __launch_bounds__(256) void k_colsum(
    const float* __restrict__ m, const unsigned* __restrict__ minkey,
    float* __restrict__ sumexp)
{
    const int col = blockIdx.x * 256 + threadIdx.x;   // gridDim.x = 4
    const int r0  = blockIdx.y * SUM_ROWS;            // gridDim.y = 256
    const float mn = kinv(minkey[col]);
    float s = 0.0f;
    for (int r = 0; r < SUM_ROWS; ++r)
        s += expf(mn - m[(size_t)(r0 + r) * PSI + col]);
    atomicAdd(&sumexp[col], s);
}

// ---------- K3: normalize in place ----------
__global__ __launch_bounds__(256) void k_norm(
    float* __restrict__ out, const unsigned* __restrict__ minkey,
    const float* __restrict__ sumexp)
{
    const size_t nf4    = (size_t)N_ROWS * PSI / 4;       // 16777216
    const size_t stride = (size_t)gridDim.x * blockDim.x; // 524288, multiple of 256
    size_t i = (size_t)blockIdx.x * blockDim.x + threadIdx.x;
    // column group is invariant across the grid-stride loop
    const int c0 = (int)(i & 255) * 4;
    float mn[4], rs[4];
    #pragma unroll
    for (int j = 0; j < 4; ++j) {
        mn[j] = kinv(minkey[c0 + j]);
        rs[j] = 1.0f / sumexp[c0 + j];
    }
    for (; i < nf4; i += stride) {
        float4 v = ((const float4*)out)[i];
        v.x = expf(mn[0] - v.x) * rs[0];
        v.y = expf(mn[1] - v.y) * rs[1];
        v.z = expf(mn[2] - v.z) * rs[2];
        v.w = expf(mn[3] - v.w) * rs[3];
        ((float4*)out)[i] = v;
    }
}

extern "C" void kernel_launch(void* const* d_in, const int* in_sizes, int n_in,
                              void* d_out, int out_size, void* d_ws, size_t ws_size,
                              hipStream_t stream) {
    const float* X = (const float*)d_in[0];
    const float* S = (const float*)d_in[1];
    const float* w = (const float*)d_in[2];
    float* out = (float*)d_out;

    unsigned* minkey = (unsigned*)d_ws;                 // 1024
    float*    sumexp = (float*)d_ws + 1024;             // 1024
    float*    x2     = (float*)d_ws + 2048;             // 65536
    float*    s2     = (float*)d_ws + 2048 + N_ROWS;    // 1024

    k_init<<<dim3(4), dim3(256), 0, stream>>>(minkey, sumexp);
    k_rownorm<<<dim3(N_ROWS / 4), dim3(256), 0, stream>>>(X, x2, N_ROWS);
    k_rownorm<<<dim3(PSI / 4), dim3(256), 0, stream>>>(S, s2, PSI);
    k_gemm_min<<<dim3(PSI / BN, N_ROWS / BM), dim3(256), 0, stream>>>(
        X, S, w, x2, s2, out, minkey);
    k_colsum<<<dim3(PSI / 256, N_ROWS / SUM_ROWS), dim3(256), 0, stream>>>(
        out, minkey, sumexp);
    k_norm<<<dim3(2048), dim3(256), 0, stream>>>(out, minkey, sumexp);
}

// Round 2
// 381.747 us; speedup vs baseline: 1.5957x; 1.5957x over previous
//
#include <hip/hip_runtime.h>
#include <hip/hip_bf16.h>
#include <math.h>

#define N_ROWS 65536
#define PSI    1024
#define DDIM   256

typedef _Float16 half8 __attribute__((ext_vector_type(8)));
typedef _Float16 half4 __attribute__((ext_vector_type(4)));
typedef float    f32x4 __attribute__((ext_vector_type(4)));

// ---------- total-order float <-> uint (all m >= 0, but keep generic) ----------
__device__ __forceinline__ unsigned fkey(float f) {
    unsigned u = __float_as_uint(f);
    return (u & 0x80000000u) ? ~u : (u | 0x80000000u);
}
__device__ __forceinline__ float kinv(unsigned k) {
    unsigned u = (k & 0x80000000u) ? (k ^ 0x80000000u) : ~k;
    return __uint_as_float(u);
}

// ---------- async global->LDS, 16B per lane ----------
__device__ __forceinline__ void gload16(const void* g, void* l) {
    __builtin_amdgcn_global_load_lds(
        (const __attribute__((address_space(1))) unsigned int*)g,
        (__attribute__((address_space(3))) unsigned int*)l, 16, 0, 0);
}

// ---------- convert f32 -> f16 + row squared-norms (f32-exact) ----------
__global__ __launch_bounds__(256) void k_convert(
    const float* __restrict__ in, _Float16* __restrict__ outh,
    float* __restrict__ nrm, int rows)
{
    const int wave = (blockIdx.x * blockDim.x + threadIdx.x) >> 6;
    const int lane = threadIdx.x & 63;
    if (wave >= rows) return;
    const float4 v = *(const float4*)&in[(size_t)wave * DDIM + lane * 4];
    float s = v.x * v.x + v.y * v.y + v.z * v.z + v.w * v.w;
    #pragma unroll
    for (int o = 32; o > 0; o >>= 1) s += __shfl_down(s, o);
    if (lane == 0) nrm[wave] = s;
    half4 h;
    h[0] = (_Float16)v.x; h[1] = (_Float16)v.y;
    h[2] = (_Float16)v.z; h[3] = (_Float16)v.w;
    *(half4*)&outh[(size_t)wave * DDIM + lane * 4] = h;
}

// ---------- MFMA GEMM, 128x128 tile, BK=32, 4 waves (2x2), 4x4 frags/wave ----
// MODE 0: per-block column stats (min, sum exp) -> pm/ps partials
// MODE 1: out = exp(mn[c] - m) * rs[c]
template<int MODE>
__global__ __launch_bounds__(256) void k_gemm(
    const _Float16* __restrict__ Xh, const _Float16* __restrict__ Sh,
    const float* __restrict__ x2, const float* __restrict__ s2,
    const float* __restrict__ w,
    float* __restrict__ pm, float* __restrict__ ps,
    const float* __restrict__ mn, const float* __restrict__ rs,
    float* __restrict__ out)
{
    __shared__ _Float16 As[128 * 32];   // 8 KB, [row][k] row-major
    __shared__ _Float16 Bs[128 * 32];   // 8 KB
    __shared__ unsigned s_mk[128];
    __shared__ float    s_sm[128];

    const int tid  = threadIdx.x;
    const int wv   = tid >> 6;
    const int wr   = wv >> 1;       // wave row half (0..1)
    const int wc   = wv & 1;        // wave col half (0..1)
    const int l15  = tid & 15;
    const int l4   = (tid & 63) >> 4;
    const int row0 = blockIdx.y * 128;
    const int col0 = blockIdx.x * 128;

    f32x4 acc[4][4];
    #pragma unroll
    for (int i = 0; i < 4; ++i)
        #pragma unroll
        for (int j = 0; j < 4; ++j) acc[i][j] = (f32x4){0.f, 0.f, 0.f, 0.f};

    // staging addresses: chunk c = tid covers row (c>>2), k-offset (c&3)*8
    const _Float16* gA = Xh + (size_t)(row0 + (tid >> 2)) * DDIM + (tid & 3) * 8;
    const _Float16* gB = Sh + (size_t)(col0 + (tid >> 2)) * DDIM + (tid & 3) * 8;
    _Float16* lA0 = As + wv * 512;          // lanes fill base + lane*16B
    _Float16* lA1 = As + 2048 + wv * 512;
    _Float16* lB0 = Bs + wv * 512;
    _Float16* lB1 = Bs + 2048 + wv * 512;

    for (int k0 = 0; k0 < DDIM; k0 += 32) {
        gload16(gA + k0,             lA0);
        gload16(gA + 64 * DDIM + k0, lA1);
        gload16(gB + k0,             lB0);
        gload16(gB + 64 * DDIM + k0, lB1);
        __syncthreads();   // vmcnt drain + barrier (compiler-emitted)
        half8 af[4], bf[4];
        #pragma unroll
        for (int f = 0; f < 4; ++f) {
            af[f] = *(const half8*)&As[(wr * 64 + f * 16 + l15) * 32 + l4 * 8];
            bf[f] = *(const half8*)&Bs[(wc * 64 + f * 16 + l15) * 32 + l4 * 8];
        }
        #pragma unroll
        for (int fm = 0; fm < 4; ++fm)
            #pragma unroll
            for (int fn = 0; fn < 4; ++fn)
                acc[fm][fn] = __builtin_amdgcn_mfma_f32_16x16x32_f16(
                    af[fm], bf[fn], acc[fm][fn], 0, 0, 0);
        __syncthreads();
    }

    // ---- epilogue ----
    if (MODE == 0) {
        if (tid < 128) { s_mk[tid] = 0xFFFFFFFFu; s_sm[tid] = 0.0f; }
        __syncthreads();
    }

    float x2r[4][4];
    #pragma unroll
    for (int fm = 0; fm < 4; ++fm)
        #pragma unroll
        for (int j = 0; j < 4; ++j)
            x2r[fm][j] = x2[row0 + wr * 64 + fm * 16 + l4 * 4 + j];

    if (MODE == 0) {
        #pragma unroll
        for (int fn = 0; fn < 4; ++fn) {
            const int cl = wc * 64 + fn * 16 + l15;
            const int c  = col0 + cl;
            const float s2c = s2[c], ww = w[c];
            float lmin = INFINITY;
            #pragma unroll
            for (int fm = 0; fm < 4; ++fm)
                #pragma unroll
                for (int j = 0; j < 4; ++j) {
                    float d2 = x2r[fm][j] + s2c - 2.0f * acc[fm][fn][j];
                    float m  = sqrtf(fmaxf(d2, 0.0f)) * ww;
                    acc[fm][fn][j] = m;        // keep m for the sum pass
                    lmin = fminf(lmin, m);
                }
            atomicMin(&s_mk[cl], fkey(lmin));
        }
        __syncthreads();
        #pragma unroll
        for (int fn = 0; fn < 4; ++fn) {
            const int cl = wc * 64 + fn * 16 + l15;
            const float g = kinv(s_mk[cl]);
            float ssum = 0.0f;
            #pragma unroll
            for (int fm = 0; fm < 4; ++fm)
                #pragma unroll
                for (int j = 0; j < 4; ++j)
                    ssum += expf(g - acc[fm][fn][j]);
            atomicAdd(&s_sm[cl], ssum);
        }
        __syncthreads();
        if (tid < 128) {
            pm[(size_t)blockIdx.y * PSI + col0 + tid] = kinv(s_mk[tid]);
            ps[(size_t)blockIdx.y * PSI + col0 + tid] = s_sm[tid];
        }
    } else {
        #pragma unroll
        for (int fn = 0; fn < 4; ++fn) {
            const int c = col0 + wc * 64 + fn * 16 + l15;
            const float s2c = s2[c], ww = w[c];
            const float mnc = mn[c], rsc = rs[c];
            #pragma unroll
            for (int fm = 0; fm < 4; ++fm)
                #pragma unroll
                for (int j = 0; j < 4; ++j) {
                    const int r = row0 + wr * 64 + fm * 16 + l4 * 4 + j;
                    float d2 = x2r[fm][j] + s2c - 2.0f * acc[fm][fn][j];
                    float m  = sqrtf(fmaxf(d2, 0.0f)) * ww;
                    out[(size_t)r * PSI + c] = expf(mnc - m) * rsc;
                }
        }
    }
}

// ---------- combine per-block partials into global (min, 1/sum) ----------
__global__ __launch_bounds__(256) void k_combine(
    const float* __restrict__ pm, const float* __restrict__ ps,
    float* __restrict__ mn, float* __restrict__ rs)
{
    const int col = blockIdx.x * 256 + threadIdx.x;   // grid 4
    float g = INFINITY;
    for (int b = 0; b < N_ROWS / 128; ++b)
        g = fminf(g, pm[(size_t)b * PSI + col]);
    float t = 0.0f;
    for (int b = 0; b < N_ROWS / 128; ++b)
        t += ps[(size_t)b * PSI + col] * expf(g - pm[(size_t)b * PSI + col]);
    mn[col] = g;
    rs[col] = 1.0f / t;
}

extern "C" void kernel_launch(void* const* d_in, const int* in_sizes, int n_in,
                              void* d_out, int out_size, void* d_ws, size_t ws_size,
                              hipStream_t stream) {
    const float* X = (const float*)d_in[0];
    const float* S = (const float*)d_in[1];
    const float* w = (const float*)d_in[2];
    float* out = (float*)d_out;

    char* ws = (char*)d_ws;
    _Float16* Xh = (_Float16*)(ws);                       // 33,554,432 B
    _Float16* Sh = (_Float16*)(ws + 33554432);            //    524,288 B
    float*    x2 = (float*)   (ws + 34078720);            //    262,144 B
    float*    s2 = (float*)   (ws + 34340864);            //      4,096 B
    float*    pm = (float*)   (ws + 34344960);            //  2,097,152 B
    float*    ps = (float*)   (ws + 36442112);            //  2,097,152 B
    float*    mn = (float*)   (ws + 38539264);            //      4,096 B
    float*    rs = (float*)   (ws + 38543360);            //      4,096 B

    k_convert<<<dim3(N_ROWS / 4), dim3(256), 0, stream>>>(X, Xh, x2, N_ROWS);
    k_convert<<<dim3(PSI / 4),    dim3(256), 0, stream>>>(S, Sh, s2, PSI);
    k_gemm<0><<<dim3(PSI / 128, N_ROWS / 128), dim3(256), 0, stream>>>(
        Xh, Sh, x2, s2, w, pm, ps, nullptr, nullptr, nullptr);
    k_combine<<<dim3(PSI / 256), dim3(256), 0, stream>>>(pm, ps, mn, rs);
    k_gemm<1><<<dim3(PSI / 128, N_ROWS / 128), dim3(256), 0, stream>>>(
        Xh, Sh, x2, s2, w, nullptr, nullptr, mn, rs, out);
}

// Round 3
// 231.493 us; speedup vs baseline: 2.6315x; 1.6491x over previous
//
#include <hip/hip_runtime.h>
#include <hip/hip_bf16.h>
#include <math.h>

#define N_ROWS 65536
#define PSI    1024
#define DDIM   256

typedef _Float16 half8 __attribute__((ext_vector_type(8)));
typedef _Float16 half4 __attribute__((ext_vector_type(4)));
typedef float    f32x4 __attribute__((ext_vector_type(4)));

// ---------- total-order float <-> uint for atomicMin ----------
__device__ __forceinline__ unsigned fkey(float f) {
    unsigned u = __float_as_uint(f);
    return (u & 0x80000000u) ? ~u : (u | 0x80000000u);
}
__device__ __forceinline__ float kinv(unsigned k) {
    unsigned u = (k & 0x80000000u) ? (k ^ 0x80000000u) : ~k;
    return __uint_as_float(u);
}

// ---------- async global->LDS, 16B per lane ----------
__device__ __forceinline__ void gload16(const void* g, void* l) {
    __builtin_amdgcn_global_load_lds(
        (const __attribute__((address_space(1))) unsigned int*)g,
        (__attribute__((address_space(3))) unsigned int*)l, 16, 0, 0);
}

// ---------- convert f32 -> f16 + row squared-norms (f32-exact) ----------
__global__ __launch_bounds__(256) void k_convert(
    const float* __restrict__ in, _Float16* __restrict__ outh,
    float* __restrict__ nrm, int rows)
{
    const int wave = (blockIdx.x * blockDim.x + threadIdx.x) >> 6;
    const int lane = threadIdx.x & 63;
    if (wave >= rows) return;
    const float4 v = *(const float4*)&in[(size_t)wave * DDIM + lane * 4];
    float s = v.x * v.x + v.y * v.y + v.z * v.z + v.w * v.w;
    #pragma unroll
    for (int o = 32; o > 0; o >>= 1) s += __shfl_down(s, o);
    if (lane == 0) nrm[wave] = s;
    half4 h;
    h[0] = (_Float16)v.x; h[1] = (_Float16)v.y;
    h[2] = (_Float16)v.z; h[3] = (_Float16)v.w;
    *(half4*)&outh[(size_t)wave * DDIM + lane * 4] = h;
}

// ---------- MFMA GEMM, 128x128 tile, BK=32, 4 waves (2x2), 4x4 frags/wave ----
// 1D grid 4096 blocks with XCD-chunked swizzle: each XCD owns 64 consecutive
// row-panels x all 8 col-blocks (cols fastest) -> A-panel L2 reuse.
// MODE 0: per-block column stats (min, sum exp) -> pm/ps partials
// MODE 1: out = exp(mn[c] - m) * rs[c]
template<int MODE>
__global__ __launch_bounds__(256) void k_gemm(
    const _Float16* __restrict__ Xh, const _Float16* __restrict__ Sh,
    const float* __restrict__ x2, const float* __restrict__ s2,
    const float* __restrict__ w,
    float* __restrict__ pm, float* __restrict__ ps,
    const float* __restrict__ mn, const float* __restrict__ rs,
    float* __restrict__ out)
{
    __shared__ _Float16 As[128 * 32];   // 8 KB, [row][k] row-major
    __shared__ _Float16 Bs[128 * 32];   // 8 KB
    __shared__ unsigned s_mk[128];
    __shared__ float    s_sm[128];

    const int tid  = threadIdx.x;
    const int wv   = tid >> 6;
    const int wr   = wv >> 1;       // wave row half (0..1)
    const int wc   = wv & 1;        // wave col half (0..1)
    const int l15  = tid & 15;
    const int l4   = (tid & 63) >> 4;

    // XCD swizzle (nwg=4096, 8 XCDs, 512 per XCD; bijective since 4096%8==0)
    const int fid   = blockIdx.x;
    const int wgid  = (fid & 7) * 512 + (fid >> 3);
    const int rowb  = wgid >> 3;            // 0..511
    const int row0  = rowb * 128;
    const int col0  = (wgid & 7) * 128;

    f32x4 acc[4][4];
    #pragma unroll
    for (int i = 0; i < 4; ++i)
        #pragma unroll
        for (int j = 0; j < 4; ++j) acc[i][j] = (f32x4){0.f, 0.f, 0.f, 0.f};

    // staging: chunk c = tid covers row (c>>2), k-offset (c&3)*8
    const _Float16* gA = Xh + (size_t)(row0 + (tid >> 2)) * DDIM + (tid & 3) * 8;
    const _Float16* gB = Sh + (size_t)(col0 + (tid >> 2)) * DDIM + (tid & 3) * 8;
    _Float16* lA0 = As + wv * 512;          // lanes fill base + lane*16B
    _Float16* lA1 = As + 2048 + wv * 512;
    _Float16* lB0 = Bs + wv * 512;
    _Float16* lB1 = Bs + 2048 + wv * 512;

    for (int k0 = 0; k0 < DDIM; k0 += 32) {
        gload16(gA + k0,             lA0);
        gload16(gA + 64 * DDIM + k0, lA1);
        gload16(gB + k0,             lB0);
        gload16(gB + 64 * DDIM + k0, lB1);
        __syncthreads();   // vmcnt drain + barrier (compiler-emitted)
        half8 af[4], bf[4];
        #pragma unroll
        for (int f = 0; f < 4; ++f) {
            af[f] = *(const half8*)&As[(wr * 64 + f * 16 + l15) * 32 + l4 * 8];
            bf[f] = *(const half8*)&Bs[(wc * 64 + f * 16 + l15) * 32 + l4 * 8];
        }
        #pragma unroll
        for (int fm = 0; fm < 4; ++fm)
            #pragma unroll
            for (int fn = 0; fn < 4; ++fn)
                acc[fm][fn] = __builtin_amdgcn_mfma_f32_16x16x32_f16(
                    af[fm], bf[fn], acc[fm][fn], 0, 0, 0);
        __syncthreads();
    }

    // ---- epilogue ----
    if (MODE == 0) {
        if (tid < 128) { s_mk[tid] = 0xFFFFFFFFu; s_sm[tid] = 0.0f; }
        __syncthreads();
    }

    float x2r[4][4];
    #pragma unroll
    for (int fm = 0; fm < 4; ++fm)
        #pragma unroll
        for (int j = 0; j < 4; ++j)
            x2r[fm][j] = x2[row0 + wr * 64 + fm * 16 + l4 * 4 + j];

    if (MODE == 0) {
        #pragma unroll
        for (int fn = 0; fn < 4; ++fn) {
            const int cl = wc * 64 + fn * 16 + l15;
            const int c  = col0 + cl;
            const float s2c = s2[c], ww = w[c];
            float lmin = INFINITY;
            #pragma unroll
            for (int fm = 0; fm < 4; ++fm)
                #pragma unroll
                for (int j = 0; j < 4; ++j) {
                    float d2 = x2r[fm][j] + s2c - 2.0f * acc[fm][fn][j];
                    float m  = sqrtf(fmaxf(d2, 0.0f)) * ww;
                    acc[fm][fn][j] = m;        // keep m for the sum pass
                    lmin = fminf(lmin, m);
                }
            atomicMin(&s_mk[cl], fkey(lmin));
        }
        __syncthreads();
        #pragma unroll
        for (int fn = 0; fn < 4; ++fn) {
            const int cl = wc * 64 + fn * 16 + l15;
            const float g = kinv(s_mk[cl]);
            float ssum = 0.0f;
            #pragma unroll
            for (int fm = 0; fm < 4; ++fm)
                #pragma unroll
                for (int j = 0; j < 4; ++j)
                    ssum += __expf(g - acc[fm][fn][j]);
            atomicAdd(&s_sm[cl], ssum);
        }
        __syncthreads();
        if (tid < 128) {
            pm[(size_t)rowb * PSI + col0 + tid] = kinv(s_mk[tid]);
            ps[(size_t)rowb * PSI + col0 + tid] = s_sm[tid];
        }
    } else {
        #pragma unroll
        for (int fn = 0; fn < 4; ++fn) {
            const int c = col0 + wc * 64 + fn * 16 + l15;
            const float s2c = s2[c], ww = w[c];
            const float mnc = mn[c], rsc = rs[c];
            #pragma unroll
            for (int fm = 0; fm < 4; ++fm)
                #pragma unroll
                for (int j = 0; j < 4; ++j) {
                    const int r = row0 + wr * 64 + fm * 16 + l4 * 4 + j;
                    float d2 = x2r[fm][j] + s2c - 2.0f * acc[fm][fn][j];
                    float m  = sqrtf(fmaxf(d2, 0.0f)) * ww;
                    out[(size_t)r * PSI + c] = __expf(mnc - m) * rsc;
                }
        }
    }
}

// ---------- combine stage 1: 8 row-chunks x 1024 cols, 32 blocks ----------
__global__ __launch_bounds__(256) void k_combine1(
    const float* __restrict__ pm, const float* __restrict__ ps,
    float* __restrict__ pm2, float* __restrict__ ps2)
{
    const int g     = blockIdx.x * 256 + threadIdx.x;   // [0, 8192)
    const int col   = g & 1023;
    const int chunk = g >> 10;                          // [0, 8)
    const int b0    = chunk * 64;
    float gm = INFINITY;
    #pragma unroll 4
    for (int b = 0; b < 64; ++b)
        gm = fminf(gm, pm[(size_t)(b0 + b) * PSI + col]);
    float t = 0.0f;
    #pragma unroll 4
    for (int b = 0; b < 64; ++b)
        t += ps[(size_t)(b0 + b) * PSI + col] * __expf(gm - pm[(size_t)(b0 + b) * PSI + col]);
    pm2[(size_t)chunk * PSI + col] = gm;
    ps2[(size_t)chunk * PSI + col] = t;
}

// ---------- combine stage 2: final (min, 1/sum) per column ----------
__global__ __launch_bounds__(256) void k_combine2(
    const float* __restrict__ pm2, const float* __restrict__ ps2,
    float* __restrict__ mn, float* __restrict__ rs)
{
    const int col = blockIdx.x * 256 + threadIdx.x;   // grid 4
    float g = INFINITY;
    #pragma unroll
    for (int b = 0; b < 8; ++b)
        g = fminf(g, pm2[(size_t)b * PSI + col]);
    float t = 0.0f;
    #pragma unroll
    for (int b = 0; b < 8; ++b)
        t += ps2[(size_t)b * PSI + col] * __expf(g - pm2[(size_t)b * PSI + col]);
    mn[col] = g;
    rs[col] = 1.0f / t;
}

extern "C" void kernel_launch(void* const* d_in, const int* in_sizes, int n_in,
                              void* d_out, int out_size, void* d_ws, size_t ws_size,
                              hipStream_t stream) {
    const float* X = (const float*)d_in[0];
    const float* S = (const float*)d_in[1];
    const float* w = (const float*)d_in[2];
    float* out = (float*)d_out;

    char* ws = (char*)d_ws;
    _Float16* Xh  = (_Float16*)(ws);                       // 33,554,432 B
    _Float16* Sh  = (_Float16*)(ws + 33554432);            //    524,288 B
    float*    x2  = (float*)   (ws + 34078720);            //    262,144 B
    float*    s2  = (float*)   (ws + 34340864);            //      4,096 B
    float*    pm  = (float*)   (ws + 34344960);            //  2,097,152 B
    float*    ps  = (float*)   (ws + 36442112);            //  2,097,152 B
    float*    mn  = (float*)   (ws + 38539264);            //      4,096 B
    float*    rs  = (float*)   (ws + 38543360);            //      4,096 B
    float*    pm2 = (float*)   (ws + 38547456);            //     32,768 B
    float*    ps2 = (float*)   (ws + 38580224);            //     32,768 B

    k_convert<<<dim3(N_ROWS / 4), dim3(256), 0, stream>>>(X, Xh, x2, N_ROWS);
    k_convert<<<dim3(PSI / 4),    dim3(256), 0, stream>>>(S, Sh, s2, PSI);
    k_gemm<0><<<dim3(4096), dim3(256), 0, stream>>>(
        Xh, Sh, x2, s2, w, pm, ps, nullptr, nullptr, nullptr);
    k_combine1<<<dim3(32), dim3(256), 0, stream>>>(pm, ps, pm2, ps2);
    k_combine2<<<dim3(PSI / 256), dim3(256), 0, stream>>>(pm2, ps2, mn, rs);
    k_gemm<1><<<dim3(4096), dim3(256), 0, stream>>>(
        Xh, Sh, x2, s2, w, nullptr, nullptr, mn, rs, out);
}

// Round 4
// 197.186 us; speedup vs baseline: 3.0893x; 1.1740x over previous
//
#include <hip/hip_runtime.h>
#include <hip/hip_bf16.h>
#include <math.h>

#define N_ROWS 65536
#define PSI    1024
#define DDIM   256

typedef _Float16 half8 __attribute__((ext_vector_type(8)));
typedef _Float16 half4 __attribute__((ext_vector_type(4)));
typedef float    f32x4 __attribute__((ext_vector_type(4)));

// ---------- total-order float <-> uint for atomicMin ----------
__device__ __forceinline__ unsigned fkey(float f) {
    unsigned u = __float_as_uint(f);
    return (u & 0x80000000u) ? ~u : (u | 0x80000000u);
}
__device__ __forceinline__ float kinv(unsigned k) {
    unsigned u = (k & 0x80000000u) ? (k ^ 0x80000000u) : ~k;
    return __uint_as_float(u);
}

// ---------- async global->LDS, 16B per lane ----------
__device__ __forceinline__ void gload16(const void* g, void* l) {
    __builtin_amdgcn_global_load_lds(
        (const __attribute__((address_space(1))) unsigned int*)g,
        (__attribute__((address_space(3))) unsigned int*)l, 16, 0, 0);
}

// ---------- convert f32 -> f16 + row squared-norms (f32-exact) ----------
__global__ __launch_bounds__(256) void k_convert(
    const float* __restrict__ in, _Float16* __restrict__ outh,
    float* __restrict__ nrm, int rows)
{
    const int wave = (blockIdx.x * blockDim.x + threadIdx.x) >> 6;
    const int lane = threadIdx.x & 63;
    if (wave >= rows) return;
    const float4 v = *(const float4*)&in[(size_t)wave * DDIM + lane * 4];
    float s = v.x * v.x + v.y * v.y + v.z * v.z + v.w * v.w;
    #pragma unroll
    for (int o = 32; o > 0; o >>= 1) s += __shfl_down(s, o);
    if (lane == 0) nrm[wave] = s;
    half4 h;
    h[0] = (_Float16)v.x; h[1] = (_Float16)v.y;
    h[2] = (_Float16)v.z; h[3] = (_Float16)v.w;
    *(half4*)&outh[(size_t)wave * DDIM + lane * 4] = h;
}

// ---------- MFMA GEMM, 128x128 tile, BK=64, double-buffered, swizzled LDS ---
// XCD-chunked 1D grid (4096): each XCD owns 64 row-panels x 8 col-blocks.
// LDS layout: [row][k] rows of 128B, XOR-swizzled byte ^= ((row&7)<<4).
// global_load_lds writes LINEAR LDS; the swizzle is applied by permuting the
// per-lane GLOBAL k-offset (rule: both-sides-or-neither).
// MODE 0: per-block column stats (min, sum exp) -> pm/ps partials
// MODE 1: out = exp(mn[c] - m) * rs[c]   (nontemporal stores)
template<int MODE>
__global__ __launch_bounds__(256) void k_gemm(
    const _Float16* __restrict__ Xh, const _Float16* __restrict__ Sh,
    const float* __restrict__ x2, const float* __restrict__ s2,
    const float* __restrict__ w,
    float* __restrict__ pm, float* __restrict__ ps,
    const float* __restrict__ mn, const float* __restrict__ rs,
    float* __restrict__ out)
{
    __shared__ _Float16 As[2][128 * 64];   // 2 x 16 KB
    __shared__ _Float16 Bs[2][128 * 64];   // 2 x 16 KB
    __shared__ unsigned s_mk[128];
    __shared__ float    s_sm[128];

    const int tid  = threadIdx.x;
    const int wv   = tid >> 6;
    const int wr   = wv >> 1;       // wave row half (0..1)
    const int wc   = wv & 1;        // wave col half (0..1)
    const int l15  = tid & 15;
    const int l4   = (tid & 63) >> 4;

    // XCD swizzle (nwg=4096 divisible by 8 -> bijective)
    const int fid   = blockIdx.x;
    const int wgid  = (fid & 7) * 512 + (fid >> 3);
    const int rowb  = wgid >> 3;            // 0..511
    const int row0  = rowb * 128;
    const int col0  = (wgid & 7) * 128;

    f32x4 acc[4][4];
    #pragma unroll
    for (int i = 0; i < 4; ++i)
        #pragma unroll
        for (int j = 0; j < 4; ++j) acc[i][j] = (f32x4){0.f, 0.f, 0.f, 0.f};

    // staging: lane tid covers row tid>>3 (of 32-row group), pre-swizzled
    // k-chunk ((tid&7)^((tid>>3)&7))*8 halfs. 8 lanes cover one 128B row.
    const int srow = tid >> 3;
    const int skq  = ((tid & 7) ^ (srow & 7)) * 8;
    const _Float16* gAp = Xh + (size_t)(row0 + srow) * DDIM + skq;
    const _Float16* gBp = Sh + (size_t)(col0 + srow) * DDIM + skq;

    auto stage = [&](int k0, int b) {
        _Float16* Ab = &As[b][wv * 512];
        _Float16* Bb = &Bs[b][wv * 512];
        #pragma unroll
        for (int rg = 0; rg < 4; ++rg)
            gload16(gAp + (size_t)(rg * 32) * DDIM + k0, Ab + rg * 2048);
        #pragma unroll
        for (int rg = 0; rg < 4; ++rg)
            gload16(gBp + (size_t)(rg * 32) * DDIM + k0, Bb + rg * 2048);
    };

    auto compute = [&](int b) {
        #pragma unroll
        for (int kk = 0; kk < 2; ++kk) {
            half8 af[4], bf[4];
            #pragma unroll
            for (int f = 0; f < 4; ++f) {
                const int swz = (l15 & 7) << 3;               // halfs
                const int ha = ((wr * 64 + f * 16 + l15) * 64 + kk * 32 + l4 * 8) ^ swz;
                const int hb = ((wc * 64 + f * 16 + l15) * 64 + kk * 32 + l4 * 8) ^ swz;
                af[f] = *(const half8*)&As[b][ha];
                bf[f] = *(const half8*)&Bs[b][hb];
            }
            #pragma unroll
            for (int fm = 0; fm < 4; ++fm)
                #pragma unroll
                for (int fn = 0; fn < 4; ++fn)
                    acc[fm][fn] = __builtin_amdgcn_mfma_f32_16x16x32_f16(
                        af[fm], bf[fn], acc[fm][fn], 0, 0, 0);
        }
    };

    stage(0, 0);
    __syncthreads();
    #pragma unroll
    for (int t = 0; t < 4; ++t) {           // K = 4 x 64
        if (t < 3) stage((t + 1) * 64, (t + 1) & 1);
        compute(t & 1);
        if (t < 3) __syncthreads();
    }

    // ---- epilogue ----
    if (MODE == 0) {
        __syncthreads();
        if (tid < 128) { s_mk[tid] = 0xFFFFFFFFu; s_sm[tid] = 0.0f; }
        __syncthreads();
    }

    float x2r[4][4];
    #pragma unroll
    for (int fm = 0; fm < 4; ++fm)
        #pragma unroll
        for (int j = 0; j < 4; ++j)
            x2r[fm][j] = x2[row0 + wr * 64 + fm * 16 + l4 * 4 + j];

    if (MODE == 0) {
        #pragma unroll
        for (int fn = 0; fn < 4; ++fn) {
            const int cl = wc * 64 + fn * 16 + l15;
            const int c  = col0 + cl;
            const float s2c = s2[c], ww = w[c];
            float lmin = INFINITY;
            #pragma unroll
            for (int fm = 0; fm < 4; ++fm)
                #pragma unroll
                for (int j = 0; j < 4; ++j) {
                    float d2 = x2r[fm][j] + s2c - 2.0f * acc[fm][fn][j];
                    float m  = sqrtf(fmaxf(d2, 0.0f)) * ww;
                    acc[fm][fn][j] = m;        // keep m for the sum pass
                    lmin = fminf(lmin, m);
                }
            atomicMin(&s_mk[cl], fkey(lmin));
        }
        __syncthreads();
        #pragma unroll
        for (int fn = 0; fn < 4; ++fn) {
            const int cl = wc * 64 + fn * 16 + l15;
            const float g = kinv(s_mk[cl]);
            float ssum = 0.0f;
            #pragma unroll
            for (int fm = 0; fm < 4; ++fm)
                #pragma unroll
                for (int j = 0; j < 4; ++j)
                    ssum += __expf(g - acc[fm][fn][j]);
            atomicAdd(&s_sm[cl], ssum);
        }
        __syncthreads();
        if (tid < 128) {
            pm[(size_t)rowb * PSI + col0 + tid] = kinv(s_mk[tid]);
            ps[(size_t)rowb * PSI + col0 + tid] = s_sm[tid];
        }
    } else {
        #pragma unroll
        for (int fn = 0; fn < 4; ++fn) {
            const int c = col0 + wc * 64 + fn * 16 + l15;
            const float s2c = s2[c], ww = w[c];
            const float mnc = mn[c], rsc = rs[c];
            #pragma unroll
            for (int fm = 0; fm < 4; ++fm)
                #pragma unroll
                for (int j = 0; j < 4; ++j) {
                    const int r = row0 + wr * 64 + fm * 16 + l4 * 4 + j;
                    float d2 = x2r[fm][j] + s2c - 2.0f * acc[fm][fn][j];
                    float m  = sqrtf(fmaxf(d2, 0.0f)) * ww;
                    __builtin_nontemporal_store(__expf(mnc - m) * rsc,
                                                &out[(size_t)r * PSI + c]);
                }
        }
    }
}

// ---------- combine stage 1: 32 row-chunks x 1024 cols, 128 blocks ----------
__global__ __launch_bounds__(256) void k_combine1(
    const float* __restrict__ pm, const float* __restrict__ ps,
    float* __restrict__ pm2, float* __restrict__ ps2)
{
    const int g     = blockIdx.x * 256 + threadIdx.x;   // [0, 32768)
    const int col   = g & 1023;
    const int chunk = g >> 10;                          // [0, 32)
    const int b0    = chunk * 16;
    float gm = INFINITY;
    #pragma unroll 4
    for (int b = 0; b < 16; ++b)
        gm = fminf(gm, pm[(size_t)(b0 + b) * PSI + col]);
    float t = 0.0f;
    #pragma unroll 4
    for (int b = 0; b < 16; ++b)
        t += ps[(size_t)(b0 + b) * PSI + col] * __expf(gm - pm[(size_t)(b0 + b) * PSI + col]);
    pm2[(size_t)chunk * PSI + col] = gm;
    ps2[(size_t)chunk * PSI + col] = t;
}

// ---------- combine stage 2: final (min, 1/sum) per column ----------
__global__ __launch_bounds__(256) void k_combine2(
    const float* __restrict__ pm2, const float* __restrict__ ps2,
    float* __restrict__ mn, float* __restrict__ rs)
{
    const int col = blockIdx.x * 256 + threadIdx.x;   // grid 4
    float g = INFINITY;
    #pragma unroll
    for (int b = 0; b < 32; ++b)
        g = fminf(g, pm2[(size_t)b * PSI + col]);
    float t = 0.0f;
    #pragma unroll
    for (int b = 0; b < 32; ++b)
        t += ps2[(size_t)b * PSI + col] * __expf(g - pm2[(size_t)b * PSI + col]);
    mn[col] = g;
    rs[col] = 1.0f / t;
}

extern "C" void kernel_launch(void* const* d_in, const int* in_sizes, int n_in,
                              void* d_out, int out_size, void* d_ws, size_t ws_size,
                              hipStream_t stream) {
    const float* X = (const float*)d_in[0];
    const float* S = (const float*)d_in[1];
    const float* w = (const float*)d_in[2];
    float* out = (float*)d_out;

    char* ws = (char*)d_ws;
    _Float16* Xh  = (_Float16*)(ws);                       // 33,554,432 B
    _Float16* Sh  = (_Float16*)(ws + 33554432);            //    524,288 B
    float*    x2  = (float*)   (ws + 34078720);            //    262,144 B
    float*    s2  = (float*)   (ws + 34340864);            //      4,096 B
    float*    pm  = (float*)   (ws + 34344960);            //  2,097,152 B
    float*    ps  = (float*)   (ws + 36442112);            //  2,097,152 B
    float*    mn  = (float*)   (ws + 38539264);            //      4,096 B
    float*    rs  = (float*)   (ws + 38543360);            //      4,096 B
    float*    pm2 = (float*)   (ws + 38547456);            //    131,072 B
    float*    ps2 = (float*)   (ws + 38678528);            //    131,072 B

    k_convert<<<dim3(N_ROWS / 4), dim3(256), 0, stream>>>(X, Xh, x2, N_ROWS);
    k_convert<<<dim3(PSI / 4),    dim3(256), 0, stream>>>(S, Sh, s2, PSI);
    k_gemm<0><<<dim3(4096), dim3(256), 0, stream>>>(
        Xh, Sh, x2, s2, w, pm, ps, nullptr, nullptr, nullptr);
    k_combine1<<<dim3(128), dim3(256), 0, stream>>>(pm, ps, pm2, ps2);
    k_combine2<<<dim3(PSI / 256), dim3(256), 0, stream>>>(pm2, ps2, mn, rs);
    k_gemm<1><<<dim3(4096), dim3(256), 0, stream>>>(
        Xh, Sh, x2, s2, w, nullptr, nullptr, mn, rs, out);
}